// Round 2
// baseline (1252.698 us; speedup 1.0000x reference)
//
#include <hip/hip_runtime.h>

// 32 chained bottleneck blocks on x[16,256,64,64] fp32.
// Phase A: h1_0 = relu(W1_0 x + b1_0)           (reads x once)
// Phase B (x32): h2_k = relu(conv3x3 h1_k), store h2_k;
//                h1_{k+1} = relu(W1_{k+1} relu(W3_k h2_k + b3_k) + b1_{k+1})
//                fused per-pixel in registers - 256-ch tensor never hits memory.
// Phase C: out = sum_k relu(W3_k h2_k + b3_k)
//
// R1 lessons: (a) phaseC acc[64] spilled to scratch (VGPR=52, WRITE=2.1GB) due
// to partially-unrolled store loop -> full unroll + launch_bounds(256,3).
// (b) phaseB was LDS-BW bound reading wave-uniform weights from LDS ->
// restructure to 1 thread = 1 pixel, uniform c-loop, weights via scalar loads.

#define NN 16
#define HH 64
#define WW 64
#define CIN 256
#define CB 4
#define NBLK 32

// ---------------- Phase A: h1_0 = relu(W1_0 . x + b1_0) ------------------
// grid (64,16): blockIdx.x = y, blockIdx.y = n. 256 threads.
__global__ __launch_bounds__(256) void phaseA(
    const float* __restrict__ x, const float* __restrict__ w1,
    const float* __restrict__ b1, float* __restrict__ h1out) {
  __shared__ float4 w1s[CIN];    // [c] -> o components
  __shared__ float4 part[4][WW]; // [chunk][px] -> o components
  int tid = threadIdx.x;
  for (int i = tid; i < CIN * CB; i += 256) {
    int o = i >> 8, c = i & 255;
    ((float*)&w1s[c])[o] = w1[i]; // w1 global layout [o][c]
  }
  __syncthreads();
  int y = blockIdx.x, n = blockIdx.y;
  int chunk = tid >> 6, px = tid & 63;
  int cbase = chunk * 64;
  const float* xp = x + ((n * CIN + cbase) * HH + y) * WW + px;
  float s0 = 0.f, s1 = 0.f, s2 = 0.f, s3 = 0.f;
#pragma unroll 8
  for (int i = 0; i < 64; ++i) {
    float xv = xp[i * HH * WW];
    float4 wv = w1s[cbase + i];
    s0 = fmaf(xv, wv.x, s0);
    s1 = fmaf(xv, wv.y, s1);
    s2 = fmaf(xv, wv.z, s2);
    s3 = fmaf(xv, wv.w, s3);
  }
  part[chunk][px] = make_float4(s0, s1, s2, s3);
  __syncthreads();
  int px2 = tid >> 2, o = tid & 3;
  float v = ((float*)&part[0][px2])[o] + ((float*)&part[1][px2])[o] +
            ((float*)&part[2][px2])[o] + ((float*)&part[3][px2])[o];
  v += b1[o];
  h1out[((n * HH + y) * WW + px2) * CB + o] = fmaxf(v, 0.f);
}

// ---------------- Phase B: one bottleneck step ---------------------------
// One thread = one pixel. 16x16 tile per block, grid (4,4,16) = 256 blocks.
// Weights read with wave-uniform indices -> scalar loads (SGPR), no LDS
// staging. LDS only holds the 18x18 h1 input tile (halo 1).
__global__ __launch_bounds__(256) void phaseB(
    const float* __restrict__ h1in, float* __restrict__ h1out,
    float* __restrict__ h2out,
    const float* __restrict__ w2, const float* __restrict__ b2,
    const float* __restrict__ w3, const float* __restrict__ b3,
    const float* __restrict__ w1n, const float* __restrict__ b1n,
    int compute_next) {
  __shared__ float4 h1t[18][18]; // input tile + halo, [y][x] -> 4 ch
  int tid = threadIdx.x;
  int tx = blockIdx.x, ty = blockIdx.y, n = blockIdx.z;
  int x0 = tx * 16, y0 = ty * 16;

  for (int t = tid; t < 324; t += 256) {
    int cy = t / 18, cx = t % 18;
    int gy = y0 + cy - 1, gx = x0 + cx - 1;
    float4 v = make_float4(0.f, 0.f, 0.f, 0.f);
    if (gy >= 0 && gy < HH && gx >= 0 && gx < WW)
      v = *(const float4*)&h1in[((n * HH + gy) * WW + gx) * CB];
    h1t[cy][cx] = v;
  }
  __syncthreads();

  int lx = tid & 15, ly = tid >> 4;

  // 3x3 conv 4->4 + bias + relu; w2 global layout [o][i][dy*3+dx] (uniform)
  float4 hacc = make_float4(b2[0], b2[1], b2[2], b2[3]);
#pragma unroll
  for (int p = 0; p < 9; ++p) {
    int dy = p / 3, dx = p % 3;
    float4 hv = h1t[ly + dy][lx + dx];
#pragma unroll
    for (int i = 0; i < 4; ++i) {
      float hvi = (i == 0) ? hv.x : (i == 1) ? hv.y : (i == 2) ? hv.z : hv.w;
      hacc.x = fmaf(hvi, w2[(0 * 4 + i) * 9 + p], hacc.x);
      hacc.y = fmaf(hvi, w2[(1 * 4 + i) * 9 + p], hacc.y);
      hacc.z = fmaf(hvi, w2[(2 * 4 + i) * 9 + p], hacc.z);
      hacc.w = fmaf(hvi, w2[(3 * 4 + i) * 9 + p], hacc.w);
    }
  }
  float4 h2 = make_float4(fmaxf(hacc.x, 0.f), fmaxf(hacc.y, 0.f),
                          fmaxf(hacc.z, 0.f), fmaxf(hacc.w, 0.f));

  int gy = y0 + ly, gx = x0 + lx;
  int pxg = (n * HH + gy) * WW + gx;
  *(float4*)&h2out[pxg * CB] = h2;

  // fused expand(W3_k)+relu+reduce(W1_{k+1}); c loop is wave-uniform ->
  // all weight loads become scalar (s_load), only FMAs hit the VALU.
  float4 t = make_float4(0.f, 0.f, 0.f, 0.f);
#pragma unroll 8
  for (int c = 0; c < 256; ++c) {
    const float4 wv = *(const float4*)&w3[c * 4]; // w3 [c][j]
    float u = fmaf(h2.w, wv.w,
              fmaf(h2.z, wv.z, fmaf(h2.y, wv.y, fmaf(h2.x, wv.x, b3[c]))));
    float v = fmaxf(u, 0.f);
    t.x = fmaf(v, w1n[c], t.x);         // w1n [o][c]
    t.y = fmaf(v, w1n[256 + c], t.y);
    t.z = fmaf(v, w1n[512 + c], t.z);
    t.w = fmaf(v, w1n[768 + c], t.w);
  }
  if (compute_next) {
    float4 r = make_float4(fmaxf(t.x + b1n[0], 0.f), fmaxf(t.y + b1n[1], 0.f),
                           fmaxf(t.z + b1n[2], 0.f), fmaxf(t.w + b1n[3], 0.f));
    *(float4*)&h1out[pxg * CB] = r;
  }
}

// ---------------- Phase C: acc = sum_k relu(W3_k h2_k + b3_k) ------------
// grid (4,16,16): x = c-chunk (64 ch), y = ygroup (4 rows), z = n.
// 256 threads: ly = tid>>6, x = tid&63. 64 reg accumulators per thread.
// Weight indices are block-uniform -> scalar loads, no LDS.
__global__ __launch_bounds__(256, 3) void phaseC(
    const float* __restrict__ h2buf, const float* __restrict__ w3g,
    const float* __restrict__ b3g, float* __restrict__ out) {
  int tid = threadIdx.x;
  int c0 = blockIdx.x * 64, yg = blockIdx.y, n = blockIdx.z;
  int ly = tid >> 6, x = tid & 63;
  int y = yg * 4 + ly;
  float acc[64];
#pragma unroll
  for (int i = 0; i < 64; ++i) acc[i] = 0.f;
  for (int k = 0; k < NBLK; ++k) {
    float4 h = *(const float4*)
        &h2buf[((((k * NN + n) * HH + y) * WW) + x) * CB];
    const float* wp = &w3g[(k * 256 + c0) * 4];
    const float* bp = &b3g[k * 256 + c0];
#pragma unroll
    for (int cl = 0; cl < 64; ++cl) {
      float u = fmaf(h.w, wp[cl * 4 + 3],
                fmaf(h.z, wp[cl * 4 + 2],
                fmaf(h.y, wp[cl * 4 + 1],
                fmaf(h.x, wp[cl * 4 + 0], bp[cl]))));
      acc[cl] += fmaxf(u, 0.f);
    }
  }
  float* op = &out[(n * CIN + c0) * (HH * WW) + y * WW + x];
#pragma unroll
  for (int cl = 0; cl < 64; ++cl)
    op[cl * (HH * WW)] = acc[cl];
}

extern "C" void kernel_launch(void* const* d_in, const int* in_sizes, int n_in,
                              void* d_out, int out_size, void* d_ws, size_t ws_size,
                              hipStream_t stream) {
  const float* x  = (const float*)d_in[0];
  const float* w1 = (const float*)d_in[1]; // [32][4][256]
  const float* b1 = (const float*)d_in[2]; // [32][4]
  const float* w2 = (const float*)d_in[3]; // [32][4][4][3][3]
  const float* b2 = (const float*)d_in[4]; // [32][4]
  const float* w3 = (const float*)d_in[5]; // [32][256][4]
  const float* b3 = (const float*)d_in[6]; // [32][256]
  float* out = (float*)d_out;
  float* ws = (float*)d_ws;

  const int STATE = NN * HH * WW * CB; // 262144 floats = 1 MiB
  float* h1a = ws;
  float* h1b = ws + STATE;
  float* h2  = ws + 2 * STATE; // 32 MiB

  phaseA<<<dim3(HH, NN), 256, 0, stream>>>(x, w1, b1, h1a);
  for (int k = 0; k < NBLK; ++k) {
    const float* hin = (k & 1) ? h1b : h1a;
    float* hout = (k & 1) ? h1a : h1b;
    int kn = (k < NBLK - 1) ? k + 1 : NBLK - 1; // wrapped, unused on last
    phaseB<<<dim3(4, 4, NN), 256, 0, stream>>>(
        hin, hout, h2 + k * STATE,
        w2 + k * 144, b2 + k * CB, w3 + k * 1024, b3 + k * 256,
        w1 + kn * 1024, b1 + kn * CB, (k < NBLK - 1) ? 1 : 0);
  }
  phaseC<<<dim3(4, 16, NN), 256, 0, stream>>>(h2, w3, b3, out);
}

// Round 3
// 654.594 us; speedup vs baseline: 1.9137x; 1.9137x over previous
//
#include <hip/hip_runtime.h>

// 32 chained bottleneck blocks on x[16,256,64,64] fp32.
// Phase A: h1_0 = relu(W1_0 x + b1_0)           (reads x once)
// Phase B (x32): h2_k = relu(conv3x3 h1_k), store h2_k;
//                h1_{k+1} = relu(W1_{k+1} relu(W3_k h2_k + b3_k) + b1_{k+1})
//                fused per-pixel; 256-ch tensor never hits memory.
// Phase C: out = sum_k relu(W3_k h2_k + b3_k)   (lane = channel)
//
// R2 lessons: scalar/SMEM weight delivery is the bottleneck in BOTH B and C.
//  - phaseB: back to LDS, but packed {w3|w1nT} pairs -> 2.25 broadcast b128/c.
//  - phaseC: lane=channel -> weights in registers (coalesced loads, zero
//    redundancy); h2 broadcast from double-buffered LDS; padded-LDS transpose
//    for coalesced stores.

#define NN 16
#define HH 64
#define WW 64
#define CIN 256
#define CB 4
#define NBLK 32
#define PXT 32  // pixels per phaseC block

// ---------------- Phase A: h1_0 = relu(W1_0 . x + b1_0) ------------------
// grid (64,16): blockIdx.x = y, blockIdx.y = n. 256 threads.
__global__ __launch_bounds__(256) void phaseA(
    const float* __restrict__ x, const float* __restrict__ w1,
    const float* __restrict__ b1, float* __restrict__ h1out) {
  __shared__ float4 w1s[CIN];    // [c] -> o components
  __shared__ float4 part[4][WW]; // [chunk][px] -> o components
  int tid = threadIdx.x;
  for (int i = tid; i < CIN * CB; i += 256) {
    int o = i >> 8, c = i & 255;
    ((float*)&w1s[c])[o] = w1[i]; // w1 global layout [o][c]
  }
  __syncthreads();
  int y = blockIdx.x, n = blockIdx.y;
  int chunk = tid >> 6, px = tid & 63;
  int cbase = chunk * 64;
  const float* xp = x + ((n * CIN + cbase) * HH + y) * WW + px;
  float s0 = 0.f, s1 = 0.f, s2 = 0.f, s3 = 0.f;
#pragma unroll 8
  for (int i = 0; i < 64; ++i) {
    float xv = xp[i * HH * WW];
    float4 wv = w1s[cbase + i];
    s0 = fmaf(xv, wv.x, s0);
    s1 = fmaf(xv, wv.y, s1);
    s2 = fmaf(xv, wv.z, s2);
    s3 = fmaf(xv, wv.w, s3);
  }
  part[chunk][px] = make_float4(s0, s1, s2, s3);
  __syncthreads();
  int px2 = tid >> 2, o = tid & 3;
  float v = ((float*)&part[0][px2])[o] + ((float*)&part[1][px2])[o] +
            ((float*)&part[2][px2])[o] + ((float*)&part[3][px2])[o];
  v += b1[o];
  h1out[((n * HH + y) * WW + px2) * CB + o] = fmaxf(v, 0.f);
}

// ---------------- Phase B: one bottleneck step ---------------------------
// Thread = pixel; 16x16 tile; grid (4,4,16) = 256 blocks.
// Weights staged ONCE per block into LDS, packed so the c-loop issues only
// 2.25 broadcast ds_read_b128 per channel (wpk[c][0]=w3[c], wpk[c][1]=w1nT[c],
// b3 four-packed).
__global__ __launch_bounds__(256) void phaseB(
    const float* __restrict__ h1in, float* __restrict__ h1out,
    float* __restrict__ h2out,
    const float* __restrict__ w2, const float* __restrict__ b2,
    const float* __restrict__ w3, const float* __restrict__ b3,
    const float* __restrict__ w1n, const float* __restrict__ b1n,
    int compute_next) {
  __shared__ float4 h1t[18][18];   // input tile + halo
  __shared__ float4 wpk[CIN][2];   // [c][0]=w3[c][j], [c][1]=w1n[o][c] transposed
  __shared__ float4 b3p[64];       // b3 packed by 4
  int tid = threadIdx.x;
  int tx = blockIdx.x, ty = blockIdx.y, n = blockIdx.z;
  int x0 = tx * 16, y0 = ty * 16;

  // stage packed weights (one c per thread)
  {
    int c = tid;
    wpk[c][0] = *(const float4*)&w3[c * 4];           // [c][j]
    float4 wt;
    wt.x = w1n[c];          // w1n global [o][c]
    wt.y = w1n[256 + c];
    wt.z = w1n[512 + c];
    wt.w = w1n[768 + c];
    wpk[c][1] = wt;
    if (tid < 64) b3p[tid] = *(const float4*)&b3[tid * 4];
  }
  // stage input tile with zero halo
  for (int t = tid; t < 324; t += 256) {
    int cy = t / 18, cx = t % 18;
    int gy = y0 + cy - 1, gx = x0 + cx - 1;
    float4 v = make_float4(0.f, 0.f, 0.f, 0.f);
    if (gy >= 0 && gy < HH && gx >= 0 && gx < WW)
      v = *(const float4*)&h1in[((n * HH + gy) * WW + gx) * CB];
    h1t[cy][cx] = v;
  }
  __syncthreads();

  int lx = tid & 15, ly = tid >> 4;

  // 3x3 conv 4->4 + bias + relu; w2 [o][i][p] uniform -> s_load, once/block
  float4 hacc = make_float4(b2[0], b2[1], b2[2], b2[3]);
#pragma unroll
  for (int p = 0; p < 9; ++p) {
    int dy = p / 3, dx = p % 3;
    float4 hv = h1t[ly + dy][lx + dx];
#pragma unroll
    for (int i = 0; i < 4; ++i) {
      float hvi = (i == 0) ? hv.x : (i == 1) ? hv.y : (i == 2) ? hv.z : hv.w;
      hacc.x = fmaf(hvi, w2[(0 * 4 + i) * 9 + p], hacc.x);
      hacc.y = fmaf(hvi, w2[(1 * 4 + i) * 9 + p], hacc.y);
      hacc.z = fmaf(hvi, w2[(2 * 4 + i) * 9 + p], hacc.z);
      hacc.w = fmaf(hvi, w2[(3 * 4 + i) * 9 + p], hacc.w);
    }
  }
  float4 h2 = make_float4(fmaxf(hacc.x, 0.f), fmaxf(hacc.y, 0.f),
                          fmaxf(hacc.z, 0.f), fmaxf(hacc.w, 0.f));

  int gy = y0 + ly, gx = x0 + lx;
  int pxg = (n * HH + gy) * WW + gx;
  *(float4*)&h2out[pxg * CB] = h2;

  // fused expand(W3_k)+relu+reduce(W1_{k+1}); broadcast LDS weight reads
  float4 t = make_float4(0.f, 0.f, 0.f, 0.f);
#pragma unroll 4
  for (int c4 = 0; c4 < 64; ++c4) {
    float4 bv = b3p[c4];
#pragma unroll
    for (int q = 0; q < 4; ++q) {
      int c = (c4 << 2) | q;
      float bq = (q == 0) ? bv.x : (q == 1) ? bv.y : (q == 2) ? bv.z : bv.w;
      float4 wv = wpk[c][0];
      float u = fmaf(h2.w, wv.w,
                fmaf(h2.z, wv.z, fmaf(h2.y, wv.y, fmaf(h2.x, wv.x, bq))));
      float v = fmaxf(u, 0.f);
      float4 wn = wpk[c][1];
      t.x = fmaf(v, wn.x, t.x);
      t.y = fmaf(v, wn.y, t.y);
      t.z = fmaf(v, wn.z, t.z);
      t.w = fmaf(v, wn.w, t.w);
    }
  }
  if (compute_next) {
    float4 r = make_float4(fmaxf(t.x + b1n[0], 0.f), fmaxf(t.y + b1n[1], 0.f),
                           fmaxf(t.z + b1n[2], 0.f), fmaxf(t.w + b1n[3], 0.f));
    *(float4*)&h1out[pxg * CB] = r;
  }
}

// ---------------- Phase C: acc = sum_k relu(W3_k h2_k + b3_k) ------------
// Lane = channel: tid = c (256 c per block), block covers PXT=32 consecutive
// pixels. Weights in registers (coalesced per-k loads), h2 broadcast from
// double-buffered LDS. Padded LDS transpose for coalesced stores.
// grid (4096/PXT=128, 16).
__global__ __launch_bounds__(256, 4) void phaseC(
    const float* __restrict__ h2buf, const float* __restrict__ w3g,
    const float* __restrict__ b3g, float* __restrict__ out) {
  __shared__ float4 h2s[2][PXT];
  __shared__ float tr[CIN][PXT + 1]; // +1 pad: bank (c+i)%32, 2-way = free
  int tid = threadIdx.x;             // channel c
  int p0 = blockIdx.x * PXT;         // flat pixel y*64+x
  int n = blockIdx.y;
  float acc[PXT];
#pragma unroll
  for (int i = 0; i < PXT; ++i) acc[i] = 0.f;

  if (tid < PXT)
    h2s[0][tid] = *(const float4*)&h2buf[((0 * NN + n) * 4096 + p0 + tid) * 4];
  __syncthreads();

  for (int k = 0; k < NBLK; ++k) {
    float4 wv = *(const float4*)&w3g[(k * 256 + tid) * 4]; // coalesced
    float bv = b3g[k * 256 + tid];
    if (k + 1 < NBLK && tid < PXT)
      h2s[(k + 1) & 1][tid] =
          *(const float4*)&h2buf[(((k + 1) * NN + n) * 4096 + p0 + tid) * 4];
    const float4* hb = h2s[k & 1];
#pragma unroll
    for (int i = 0; i < PXT; ++i) {
      float4 h = hb[i]; // broadcast ds_read_b128
      float u = fmaf(h.w, wv.w,
                fmaf(h.z, wv.z, fmaf(h.y, wv.y, fmaf(h.x, wv.x, bv))));
      acc[i] += fmaxf(u, 0.f);
    }
    __syncthreads();
  }

  // transpose in LDS -> coalesced stores
#pragma unroll
  for (int i = 0; i < PXT; ++i) tr[tid][i] = acc[i];
  __syncthreads();
  int xi = tid & 31, cb = tid >> 5; // 8 channel-groups per pass
#pragma unroll
  for (int j = 0; j < 32; ++j) {
    int c = cb + j * 8;
    out[(n * CIN + c) * (HH * WW) + p0 + xi] = tr[c][xi];
  }
}

extern "C" void kernel_launch(void* const* d_in, const int* in_sizes, int n_in,
                              void* d_out, int out_size, void* d_ws, size_t ws_size,
                              hipStream_t stream) {
  const float* x  = (const float*)d_in[0];
  const float* w1 = (const float*)d_in[1]; // [32][4][256]
  const float* b1 = (const float*)d_in[2]; // [32][4]
  const float* w2 = (const float*)d_in[3]; // [32][4][4][3][3]
  const float* b2 = (const float*)d_in[4]; // [32][4]
  const float* w3 = (const float*)d_in[5]; // [32][256][4]
  const float* b3 = (const float*)d_in[6]; // [32][256]
  float* out = (float*)d_out;
  float* ws = (float*)d_ws;

  const int STATE = NN * HH * WW * CB; // 262144 floats = 1 MiB
  float* h1a = ws;
  float* h1b = ws + STATE;
  float* h2  = ws + 2 * STATE; // 32 MiB

  phaseA<<<dim3(HH, NN), 256, 0, stream>>>(x, w1, b1, h1a);
  for (int k = 0; k < NBLK; ++k) {
    const float* hin = (k & 1) ? h1b : h1a;
    float* hout = (k & 1) ? h1a : h1b;
    int kn = (k < NBLK - 1) ? k + 1 : NBLK - 1; // wrapped, unused on last
    phaseB<<<dim3(4, 4, NN), 256, 0, stream>>>(
        hin, hout, h2 + k * STATE,
        w2 + k * 144, b2 + k * CB, w3 + k * 1024, b3 + k * 256,
        w1 + kn * 1024, b1 + kn * CB, (k < NBLK - 1) ? 1 : 0);
  }
  phaseC<<<dim3((HH * WW) / PXT, NN), 256, 0, stream>>>(h2, w3, b3, out);
}